// Round 4
// baseline (460.438 us; speedup 1.0000x reference)
//
#include <hip/hip_runtime.h>

#define D_IN 128
#define D_OUT 64
#define NSLICE 8
#define NBLK 1024   // blocks for hist/partition kernels

// --- bf16 helpers ----------------------------------------------------------
__device__ inline float bf2f(unsigned short u) {
    union { unsigned int i; float f; } v; v.i = ((unsigned int)u) << 16; return v.f;
}
__device__ inline unsigned short f2bf(float f) {
    union { float f; unsigned int i; } v; v.f = f;
    unsigned int r = v.i + 0x7fffu + ((v.i >> 16) & 1u);
    return (unsigned short)(r >> 16);
}
__device__ inline float u2f(unsigned int u) {
    union { unsigned int i; float f; } v; v.i = u; return v.f;
}

// slice of row rw via magic multiply (exact for n < 2^19, see host side)
__device__ inline int slice_of(int rw, unsigned int magic) {
    return (int)(((unsigned long long)(unsigned int)rw * magic) >> 35);
}

// ---------------------------------------------------------------------------
// K1: per-block-per-slice histogram of edge targets + fused degree count.
//     bcnt layout is SLICE-MAJOR: bcnt[s*NBLK + b].
// ---------------------------------------------------------------------------
__global__ __launch_bounds__(256) void k_hist(
    const int* __restrict__ row, unsigned int* __restrict__ deg,
    unsigned int* __restrict__ bcnt, int E, unsigned int magic) {
    __shared__ unsigned int cnt[NSLICE];
    if (threadIdx.x < NSLICE) cnt[threadIdx.x] = 0;
    __syncthreads();
    const int chunk = (E + NBLK - 1) / NBLK;
    const int lo = blockIdx.x * chunk;
    const int hi = min(E, lo + chunk);
    for (int e = lo + threadIdx.x; e < hi; e += 256) {
        int rw = __builtin_nontemporal_load(&row[e]);
        int s = slice_of(rw, magic);
        atomicAdd(&cnt[s], 1u);
        atomicAdd(&deg[rw], 1u);
    }
    __syncthreads();
    if (threadIdx.x < NSLICE)
        bcnt[threadIdx.x * NBLK + blockIdx.x] = cnt[threadIdx.x];
}

// ---------------------------------------------------------------------------
// K2: exclusive scan of bcnt[8*NBLK] in place. 1 block, 1024 threads x 8.
// ---------------------------------------------------------------------------
__global__ __launch_bounds__(1024) void k_scanb(unsigned int* __restrict__ bcnt) {
    __shared__ unsigned int tsum[1024];
    const int t = threadIdx.x;
    unsigned int v[8];
    unsigned int s8 = 0;
#pragma unroll
    for (int k = 0; k < 8; ++k) { v[k] = bcnt[t * 8 + k]; s8 += v[k]; }
    tsum[t] = s8;
    __syncthreads();
    for (int off = 1; off < 1024; off <<= 1) {
        unsigned int u = (t >= off) ? tsum[t - off] : 0;
        __syncthreads();
        tsum[t] += u;
        __syncthreads();
    }
    unsigned int run = tsum[t] - s8;  // exclusive prefix of this 8-group
#pragma unroll
    for (int k = 0; k < 8; ++k) { bcnt[t * 8 + k] = run; run += v[k]; }
}

// ---------------------------------------------------------------------------
// scans for row_ptr (same as before)
// ---------------------------------------------------------------------------
__global__ void k_scan1(const unsigned int* __restrict__ deg, int* __restrict__ excl,
                        int* __restrict__ bsums, int n) {
    __shared__ int tmp[256];
    int tid = threadIdx.x;
    int i = blockIdx.x * 256 + tid;
    int v = (i < n) ? (int)deg[i] : 0;
    tmp[tid] = v;
    __syncthreads();
    for (int off = 1; off < 256; off <<= 1) {
        int t = (tid >= off) ? tmp[tid - off] : 0;
        __syncthreads();
        tmp[tid] += t;
        __syncthreads();
    }
    if (i < n) excl[i] = tmp[tid] - v;
    if (tid == 255) bsums[blockIdx.x] = tmp[255];
}

__global__ void k_scan2(int* __restrict__ bsums, int nb) {
    __shared__ int tmp[512];
    int tid = threadIdx.x;
    int v = (tid < nb) ? bsums[tid] : 0;
    tmp[tid] = v;
    __syncthreads();
    for (int off = 1; off < 512; off <<= 1) {
        int t = (tid >= off) ? tmp[tid - off] : 0;
        __syncthreads();
        tmp[tid] += t;
        __syncthreads();
    }
    if (tid < nb) bsums[tid] = tmp[tid] - v;
}

__global__ void k_scan3(int* __restrict__ row_ptr, const int* __restrict__ bsums,
                        int* __restrict__ cursor, const unsigned int* __restrict__ deg,
                        float* __restrict__ dinv, int n, int E) {
    int i = blockIdx.x * 256 + threadIdx.x;
    if (i < n) {
        int rp = row_ptr[i] + bsums[i >> 8];
        row_ptr[i] = rp;
        cursor[i] = rp;
        dinv[i] = rsqrtf((float)(deg[i] + 1u));
    }
    if (i == 0) row_ptr[n] = E;
}

// ---------------------------------------------------------------------------
// K3: partition edges into slice-major pair buckets; per-(block,slice)
//     ranges are contiguous -> coalescing writes, no amplification.
// ---------------------------------------------------------------------------
__global__ __launch_bounds__(256) void k_part(
    const int* __restrict__ row, const int* __restrict__ col,
    const unsigned int* __restrict__ bcnt, int2* __restrict__ pairs,
    int E, unsigned int magic) {
    __shared__ unsigned int cur[NSLICE];
    if (threadIdx.x < NSLICE)
        cur[threadIdx.x] = bcnt[threadIdx.x * NBLK + blockIdx.x];
    __syncthreads();
    const int chunk = (E + NBLK - 1) / NBLK;
    const int lo = blockIdx.x * chunk;
    const int hi = min(E, lo + chunk);
    for (int e = lo + threadIdx.x; e < hi; e += 256) {
        int rw = __builtin_nontemporal_load(&row[e]);
        int cw = __builtin_nontemporal_load(&col[e]);
        int s = slice_of(rw, magic);
        unsigned int pos = atomicAdd(&cur[s], 1u);
        pairs[pos] = make_int2(rw, cw);
    }
}

// ---------------------------------------------------------------------------
// K4: per-slice counting-sort scatter. Slice s blocks (bid&7, XCD-affine)
//     read only their contiguous 3.2 MB pair range; scol writes confined to
//     the slice's 1.6 MB window with minimal streaming pressure.
// ---------------------------------------------------------------------------
__global__ __launch_bounds__(256) void k_scatter2(
    const int2* __restrict__ pairs, const unsigned int* __restrict__ bcnt,
    int* __restrict__ cursor, int* __restrict__ scol, int E) {
    const int s = blockIdx.x & (NSLICE - 1);
    const unsigned int beg = bcnt[s * NBLK];
    const unsigned int end = (s == NSLICE - 1) ? (unsigned int)E : bcnt[(s + 1) * NBLK];
    const int gsz = (gridDim.x / NSLICE) * blockDim.x;
    unsigned int i = beg + (blockIdx.x / NSLICE) * blockDim.x + threadIdx.x;
    for (; i < end; i += gsz) {
        int2 p = pairs[i];
        int pos = atomicAdd(&cursor[p.x], 1);
        scol[pos] = p.y;
    }
}

// ---------------------------------------------------------------------------
// legacy fallback (round-3 path) if ws_size is too small for the pair buffer
// ---------------------------------------------------------------------------
__global__ void k_count_legacy(const int* __restrict__ row, unsigned int* __restrict__ deg, int E) {
    int e = blockIdx.x * blockDim.x + threadIdx.x;
    int stride = gridDim.x * blockDim.x;
    for (; e < E; e += stride) atomicAdd(&deg[__builtin_nontemporal_load(&row[e])], 1u);
}
__global__ void k_bucket_legacy(const int* __restrict__ row, const int* __restrict__ col,
                                int* __restrict__ cursor, int* __restrict__ scol,
                                int E, int n) {
    const int slice = blockIdx.x & (NSLICE - 1);
    const int lo = (int)((long long)n * slice / NSLICE);
    const int hi = (int)((long long)n * (slice + 1) / NSLICE);
    const int gsz = (gridDim.x / NSLICE) * blockDim.x;
    int gid = (blockIdx.x / NSLICE) * blockDim.x + threadIdx.x;
    for (int e = gid; e < E; e += gsz) {
        int rw = __builtin_nontemporal_load(&row[e]);
        if (rw >= lo && rw < hi) {
            int c = __builtin_nontemporal_load(&col[e]);
            int pos = atomicAdd(&cursor[rw], 1);
            scol[pos] = c;
        }
    }
}

// ---------------------------------------------------------------------------
// GEMM: h[i][:] = bf16( dinv[i] * (x[i] @ W) ), 4 rows per wave.
// ---------------------------------------------------------------------------
__global__ __launch_bounds__(256) void k_gemm(
    const float* __restrict__ x, const float* __restrict__ W,
    const float* __restrict__ dinv, unsigned short* __restrict__ h, int n) {
    __shared__ float Ws[D_IN * D_OUT];
    __shared__ float xs[4][4][D_IN];
    for (int idx = threadIdx.x; idx < D_IN * D_OUT; idx += 256)
        Ws[idx] = W[idx];
    __syncthreads();

    const int wave = threadIdx.x >> 6;
    const int lane = threadIdx.x & 63;
    float* xw = &xs[wave][0][0];

    for (int i0 = (blockIdx.x * 4 + wave) * 4; i0 < n; i0 += gridDim.x * 16) {
#pragma unroll
        for (int r = 0; r < 4; ++r) {
            int i = min(i0 + r, n - 1);
            *(float2*)&xw[r * D_IN + lane * 2] =
                *(const float2*)&x[(size_t)i * D_IN + lane * 2];
        }
        float a0 = 0.f, a1 = 0.f, a2 = 0.f, a3 = 0.f;
#pragma unroll
        for (int k4 = 0; k4 < D_IN; k4 += 4) {
            float4 x0 = *(float4*)&xw[0 * D_IN + k4];
            float4 x1 = *(float4*)&xw[1 * D_IN + k4];
            float4 x2 = *(float4*)&xw[2 * D_IN + k4];
            float4 x3 = *(float4*)&xw[3 * D_IN + k4];
#pragma unroll
            for (int u = 0; u < 4; ++u) {
                float wv = Ws[(k4 + u) * D_OUT + lane];
                a0 = fmaf((&x0.x)[u], wv, a0);
                a1 = fmaf((&x1.x)[u], wv, a1);
                a2 = fmaf((&x2.x)[u], wv, a2);
                a3 = fmaf((&x3.x)[u], wv, a3);
            }
        }
        int nr = min(4, n - i0);
        if (nr == 4) {
            h[(size_t)(i0 + 0) * D_OUT + lane] = f2bf(dinv[i0 + 0] * a0);
            h[(size_t)(i0 + 1) * D_OUT + lane] = f2bf(dinv[i0 + 1] * a1);
            h[(size_t)(i0 + 2) * D_OUT + lane] = f2bf(dinv[i0 + 2] * a2);
            h[(size_t)(i0 + 3) * D_OUT + lane] = f2bf(dinv[i0 + 3] * a3);
        } else {
            for (int r = 0; r < nr; ++r) {
                float a = (r == 0) ? a0 : (r == 1) ? a1 : (r == 2) ? a2 : a3;
                h[(size_t)(i0 + r) * D_OUT + lane] = f2bf(dinv[i0 + r] * a);
            }
        }
    }
}

// ---------------------------------------------------------------------------
// Aggregation v2: one wave per node; TWO edges per gather round.
//   lane = 32*half + l31; each lane loads one uint (2 bf16 feats) of one
//   edge's h row: half 0 covers even-numbered edges, half 1 odd-numbered.
//   Halves combined with one shfl_xor(32) at the end; self term added after.
// ---------------------------------------------------------------------------
__global__ __launch_bounds__(256) void k_aggr(
    const unsigned short* __restrict__ h, const int* __restrict__ row_ptr,
    const int* __restrict__ scol, const float* __restrict__ dinv,
    const float* __restrict__ b, float* __restrict__ out, int n) {
    const int wave = threadIdx.x >> 6;
    const int lane = threadIdx.x & 63;
    const int half = lane >> 5;
    const int l31 = lane & 31;
    const int i = blockIdx.x * 4 + wave;
    if (i >= n) return;

    const unsigned int* hp = (const unsigned int*)h;  // 32 uints per row
    float ax = 0.f, ay = 0.f;

    const int beg = row_ptr[i];
    const int end = row_ptr[i + 1];
    int base = beg;
    // full 64-edge chunks: 32 pair-rounds, no guards
    for (; base + 64 <= end; base += 64) {
        const int c = __builtin_nontemporal_load(&scol[base + lane]);
#pragma unroll
        for (int jp = 0; jp < 32; ++jp) {
            int cj = __shfl(c, 2 * jp + half);
            unsigned int u = hp[(size_t)cj * 32 + l31];
            ax += u2f(u << 16);
            ay += u2f(u & 0xffff0000u);
        }
    }
    // tail
    const int rem = end - base;
    if (rem > 0) {
        const int c = __builtin_nontemporal_load(&scol[base + min(lane, rem - 1)]);
        const int pairs = (rem + 1) >> 1;
        for (int jp = 0; jp < pairs; ++jp) {
            int ep = 2 * jp + half;
            int cj = __shfl(c, min(ep, rem - 1));  // shfl outside guard: src always active
            if (ep < rem) {
                unsigned int u = hp[(size_t)cj * 32 + l31];
                ax += u2f(u << 16);
                ay += u2f(u & 0xffff0000u);
            }
        }
    }
    // combine halves
    ax += __shfl_xor(ax, 32);
    ay += __shfl_xor(ay, 32);
    // self term + finalize (all lanes compute; half 0 stores)
    unsigned int us = hp[(size_t)i * 32 + l31];
    ax += u2f(us << 16);
    ay += u2f(us & 0xffff0000u);
    float d = dinv[i];
    float2 bb = *(const float2*)&b[l31 * 2];
    float2 r;
    r.x = fmaxf(fmaf(d, ax, bb.x), 0.f);
    r.y = fmaxf(fmaf(d, ay, bb.y), 0.f);
    if (half == 0)
        *(float2*)&out[(size_t)i * D_OUT + l31 * 2] = r;
}

extern "C" void kernel_launch(void* const* d_in, const int* in_sizes, int n_in,
                              void* d_out, int out_size, void* d_ws, size_t ws_size,
                              hipStream_t stream) {
    const float* x  = (const float*)d_in[0];
    const int*   ei = (const int*)d_in[1];   // [2][E] int32: row=targets, col=sources
    const float* W  = (const float*)d_in[2];
    const float* b  = (const float*)d_in[3];
    const int n = in_sizes[0] / D_IN;   // 100000
    const int E = in_sizes[1] / 2;      // 3200000
    const int* row = ei;
    const int* col = ei + E;

    char* base = (char*)d_ws;
    size_t off = 0;
    auto alloc = [&](size_t bytes) { char* p = base + off; off += (bytes + 63) & ~(size_t)63; return p; };
    unsigned short* h       = (unsigned short*)alloc((size_t)n * D_OUT * 2); // 12.8 MB
    int*            scol    = (int*)alloc((size_t)E * 4);                    // 12.8 MB
    unsigned int*   deg     = (unsigned int*)alloc((size_t)n * 4);
    int*            row_ptr = (int*)alloc(((size_t)n + 1) * 4);
    int*            cursor  = (int*)alloc((size_t)n * 4);
    float*          dinv    = (float*)alloc((size_t)n * 4);
    int*            bsums   = (int*)alloc(512 * 4);
    unsigned int*   bcnt    = (unsigned int*)alloc((size_t)NSLICE * NBLK * 4); // 32 KB
    size_t need_base = off;
    int2*           pairs   = (int2*)alloc((size_t)E * 8);                   // 25.6 MB
    const bool have_pairs = (off <= ws_size);

    const int NB = (n + 255) / 256;  // 391 <= 512
    // slice divisor magic: slice = (rw * magic) >> 35, DIV = ceil(n/8).
    // Exact for n < 2^19 (rw*(magic*DIV - 2^35) < 8*DIV^2 < 2^35).
    const unsigned int DIV = (unsigned int)((n + NSLICE - 1) / NSLICE);
    const unsigned int magic = (unsigned int)(((1ULL << 35) + DIV - 1) / DIV);

    hipMemsetAsync(deg, 0, (size_t)n * sizeof(unsigned int), stream);
    if (have_pairs) {
        k_hist<<<NBLK, 256, 0, stream>>>(row, deg, bcnt, E, magic);
        k_scanb<<<1, 1024, 0, stream>>>(bcnt);
        k_scan1<<<NB, 256, 0, stream>>>(deg, row_ptr, bsums, n);
        k_scan2<<<1, 512, 0, stream>>>(bsums, NB);
        k_scan3<<<NB, 256, 0, stream>>>(row_ptr, bsums, cursor, deg, dinv, n, E);
        k_part<<<NBLK, 256, 0, stream>>>(row, col, bcnt, pairs, E, magic);
        k_gemm<<<2048, 256, 0, stream>>>(x, W, dinv, h, n);
        k_scatter2<<<2048, 256, 0, stream>>>(pairs, bcnt, cursor, scol, E);
    } else {
        (void)need_base;
        k_count_legacy<<<2048, 256, 0, stream>>>(row, deg, E);
        k_scan1<<<NB, 256, 0, stream>>>(deg, row_ptr, bsums, n);
        k_scan2<<<1, 512, 0, stream>>>(bsums, NB);
        k_scan3<<<NB, 256, 0, stream>>>(row_ptr, bsums, cursor, deg, dinv, n, E);
        k_gemm<<<2048, 256, 0, stream>>>(x, W, dinv, h, n);
        k_bucket_legacy<<<2048, 256, 0, stream>>>(row, col, cursor, scol, E, n);
    }
    k_aggr<<<(n + 3) / 4, 256, 0, stream>>>(h, row_ptr, scol, dinv, b, (float*)d_out, n);
}